// Round 1
// baseline (4419.884 us; speedup 1.0000x reference)
//
#include <hip/hip_runtime.h>
#include <math.h>

#define NHEADS 16
#define HS     128   // head_size
#define NOPT   512   // options
#define TB     16    // tokens per block
#define EMB    2048  // n_heads * head_size

// 256 threads = 4 waves. Thread (tok = t>>4, og = t&15).
// Each block: one head, TB tokens.
__global__ __launch_bounds__(256, 2) void vq_fwd(
    const float* __restrict__ x,     // [8192][2048]
    const float* __restrict__ W,     // [16][512][128]
    const float* __restrict__ C,     // [16][512][128]
    const float* __restrict__ temp,  // [1]
    float* __restrict__ out)         // [8192][2048]
{
    __shared__ float x_lds[TB][HS + 4];    // +4 pad: tok rows spread across banks
    __shared__ float l_lds[TB][NOPT + 4];  // stride 516 -> 2-way (free)

    const int b    = blockIdx.x;
    // XCD-aware: blockIdx%8 ~ XCD; give each XCD 2 heads so W+C (1MB) fits its L2.
    const int h    = ((b & 7) << 1) | ((b >> 3) & 1);
    const int tile = b >> 4;
    const int n0   = tile * TB;
    const int t    = threadIdx.x;
    const int tok  = t >> 4;
    const int og   = t & 15;
    const float invT = 1.0f / temp[0];

    // ---- stage x tile (coalesced float4) ----
    for (int f = t; f < TB * HS / 4; f += 256) {
        const int tk = f >> 5;   // 32 float4 per token row
        const int i4 = f & 31;
        const float4 v = *(const float4*)(x + (size_t)(n0 + tk) * EMB + h * HS + i4 * 4);
        *(float4*)&x_lds[tk][i4 * 4] = v;
    }
    __syncthreads();

    // ---- phase 1: logits[tok][o] = dot(x[tok], W[h][o]) * invT ----
    // thread covers o = og + 16*m, m = mb*8+mm. mb-blocking keeps the live W
    // footprint at 128 rows * 128B line = 16KB so L1 captures line reuse.
    const float* __restrict__ Wh = W + (size_t)h * NOPT * HS;
    for (int mb = 0; mb < 4; ++mb) {
        float acc[8];
        #pragma unroll
        for (int mm = 0; mm < 8; ++mm) acc[mm] = 0.0f;
        for (int i4 = 0; i4 < HS / 4; ++i4) {
            const float4 xv = *(const float4*)&x_lds[tok][i4 * 4];
            #pragma unroll
            for (int mm = 0; mm < 8; ++mm) {
                const int o = og + 16 * (mb * 8 + mm);
                const float4 wv = *(const float4*)(Wh + (size_t)o * HS + i4 * 4);
                acc[mm] = fmaf(xv.x, wv.x, acc[mm]);
                acc[mm] = fmaf(xv.y, wv.y, acc[mm]);
                acc[mm] = fmaf(xv.z, wv.z, acc[mm]);
                acc[mm] = fmaf(xv.w, wv.w, acc[mm]);
            }
        }
        #pragma unroll
        for (int mm = 0; mm < 8; ++mm)
            l_lds[tok][og + 16 * (mb * 8 + mm)] = acc[mm] * invT;
    }
    __syncthreads();

    // ---- phase 2: softmax over 512 options (16 lanes per token) ----
    float mx = -INFINITY;
    for (int k = 0; k < 32; ++k) mx = fmaxf(mx, l_lds[tok][og + 16 * k]);
    #pragma unroll
    for (int s = 1; s < 16; s <<= 1) mx = fmaxf(mx, __shfl_xor(mx, s));
    float sum = 0.0f;
    for (int k = 0; k < 32; ++k) {
        const float p = __expf(l_lds[tok][og + 16 * k] - mx);
        l_lds[tok][og + 16 * k] = p;   // store unnormalized; fold 1/sum at the end
        sum += p;
    }
    #pragma unroll
    for (int s = 1; s < 16; s <<= 1) sum += __shfl_xor(sum, s);
    const float rs = 1.0f / sum;
    __syncthreads();

    // ---- phase 3: out[tok][a] = sum_o p[tok][o] * C[h][o][a], a = og*8..og*8+7 ----
    const float* __restrict__ Ch = C + (size_t)h * NOPT * HS;
    const int a0 = og * 8;
    float oa[8];
    #pragma unroll
    for (int j = 0; j < 8; ++j) oa[j] = 0.0f;
    for (int o = 0; o < NOPT; ++o) {
        const float p = l_lds[tok][o];                      // broadcast across og
        const float4 c0 = *(const float4*)(Ch + (size_t)o * HS + a0);
        const float4 c1 = *(const float4*)(Ch + (size_t)o * HS + a0 + 4);
        oa[0] = fmaf(p, c0.x, oa[0]);
        oa[1] = fmaf(p, c0.y, oa[1]);
        oa[2] = fmaf(p, c0.z, oa[2]);
        oa[3] = fmaf(p, c0.w, oa[3]);
        oa[4] = fmaf(p, c1.x, oa[4]);
        oa[5] = fmaf(p, c1.y, oa[5]);
        oa[6] = fmaf(p, c1.z, oa[6]);
        oa[7] = fmaf(p, c1.w, oa[7]);
    }
    float* op = out + (size_t)(n0 + tok) * EMB + h * HS + a0;
    float4 r0, r1;
    r0.x = oa[0] * rs; r0.y = oa[1] * rs; r0.z = oa[2] * rs; r0.w = oa[3] * rs;
    r1.x = oa[4] * rs; r1.y = oa[5] * rs; r1.z = oa[6] * rs; r1.w = oa[7] * rs;
    *(float4*)op       = r0;
    *(float4*)(op + 4) = r1;
}

extern "C" void kernel_launch(void* const* d_in, const int* in_sizes, int n_in,
                              void* d_out, int out_size, void* d_ws, size_t ws_size,
                              hipStream_t stream) {
    const float* x  = (const float*)d_in[0];
    const float* W  = (const float*)d_in[1];
    const float* C  = (const float*)d_in[2];
    const float* T  = (const float*)d_in[3];
    float* out      = (float*)d_out;

    const int ntok = in_sizes[0] / EMB;          // 8192
    const int nblk = (ntok / TB) * NHEADS;       // 8192
    hipLaunchKernelGGL(vq_fwd, dim3(nblk), dim3(256), 0, stream,
                       x, W, C, T, out);
}

// Round 2
// 164.330 us; speedup vs baseline: 26.8964x; 26.8964x over previous
//
#include <hip/hip_runtime.h>
#include <math.h>

#define NHEADS 16
#define HS     128
#define NOPT   512
#define TB     64    // tokens per block (4 waves x 16)
#define KVB    64    // option chunk
#define EMB    2048
#define LOG2E  1.44269504088896340736f

typedef short bf16x8 __attribute__((ext_vector_type(8)));
typedef unsigned short u16x8 __attribute__((ext_vector_type(8)));
typedef float f32x4 __attribute__((ext_vector_type(4)));

__device__ __forceinline__ unsigned short f2bf(float f) {
    union { float f; unsigned u; } v; v.f = f;
    unsigned r = v.u + 0x7FFFu + ((v.u >> 16) & 1u);   // rn-even
    return (unsigned short)(r >> 16);
}
__device__ __forceinline__ float bf2f(unsigned short h) {
    union { unsigned u; float f; } v; v.u = ((unsigned)h) << 16;
    return v.f;
}

// Per block: 64 tokens x 1 head. Wave w owns tokens [w*16, w*16+16) x all 512 options.
// Phase 1: logits via hi/lo-split bf16 MFMA (3 products). Phase 2: in-register softmax.
// Phase 3: out = P @ C with C^T staged in LDS chunk-wise.
__global__ __launch_bounds__(256, 2) void vq_fwd_mfma(
    const float* __restrict__ x, const float* __restrict__ W,
    const float* __restrict__ C, const float* __restrict__ temp,
    float* __restrict__ out)
{
    __shared__ unsigned short xh_lds[TB * HS];     // 16 KB
    __shared__ unsigned short xl_lds[TB * HS];     // 16 KB
    __shared__ unsigned short wst[2][KVB * HS];    // 32 KB: W hi/lo; reused as C^T[128][64]
    __shared__ unsigned short p_lds[4][16 * KVB];  // 8 KB: per-wave P chunk

    const int t  = threadIdx.x;
    const int l  = t & 63;
    const int w  = t >> 6;
    const int lr = l & 15;   // fragment "row/col" lane id
    const int lk = l >> 4;   // k-group
    const int b  = blockIdx.x;
    // XCD swizzle: b&7 ~ XCD; each XCD sees 2 heads -> W+C (2 MB fp32) fits its L2.
    const int h    = ((b & 7) << 1) | ((b >> 3) & 1);
    const int tile = b >> 4;               // 0..127
    const int n0   = tile * TB;
    const float invT = 1.0f / temp[0];

    // ---- stage x tile: xh/xl [64][128] bf16, XOR-swizzled (col ^= (row&7)<<3) ----
    #pragma unroll
    for (int kk = 0; kk < 4; ++kk) {
        const int g = t + 256 * kk;        // 1024 groups of 8
        const int row = g >> 4, c8 = (g & 15) * 8;
        const float* src = x + (size_t)(n0 + row) * EMB + h * HS + c8;
        const float4 v0 = *(const float4*)src;
        const float4 v1 = *(const float4*)(src + 4);
        float vv[8] = {v0.x, v0.y, v0.z, v0.w, v1.x, v1.y, v1.z, v1.w};
        u16x8 hh, ll;
        #pragma unroll
        for (int j = 0; j < 8; ++j) {
            const unsigned short hb = f2bf(vv[j]);
            hh[j] = hb;
            ll[j] = f2bf(vv[j] - bf2f(hb));
        }
        const int idx = row * HS + (c8 ^ ((row & 7) << 3));
        *(u16x8*)&xh_lds[idx] = hh;
        *(u16x8*)&xl_lds[idx] = ll;
    }

    f32x4 acc[32];
    #pragma unroll
    for (int i = 0; i < 32; ++i) acc[i] = f32x4{0.f, 0.f, 0.f, 0.f};

    bf16x8 axh[4], axl[4];

    // ================= Phase 1: logits =================
    #pragma unroll
    for (int c = 0; c < 8; ++c) {
        if (c) __syncthreads();            // prior chunk's MFMA reads done
        #pragma unroll
        for (int kk = 0; kk < 4; ++kk) {   // stage W chunk hi+lo
            const int g = t + 256 * kk;
            const int row = g >> 4, c8 = (g & 15) * 8;
            const float* src = W + ((size_t)h * NOPT + c * KVB + row) * HS + c8;
            const float4 v0 = *(const float4*)src;
            const float4 v1 = *(const float4*)(src + 4);
            float vv[8] = {v0.x, v0.y, v0.z, v0.w, v1.x, v1.y, v1.z, v1.w};
            u16x8 hh, ll;
            #pragma unroll
            for (int j = 0; j < 8; ++j) {
                const unsigned short hb = f2bf(vv[j]);
                hh[j] = hb;
                ll[j] = f2bf(vv[j] - bf2f(hb));
            }
            const int idx = row * HS + (c8 ^ ((row & 7) << 3));
            *(u16x8*)&wst[0][idx] = hh;
            *(u16x8*)&wst[1][idx] = ll;
        }
        __syncthreads();
        if (c == 0) {                      // A-frags constant across chunks
            const int arow = w * 16 + lr;
            #pragma unroll
            for (int ks = 0; ks < 4; ++ks) {
                const int ai = arow * HS + ((lk * 8 + ks * 32) ^ ((arow & 7) << 3));
                axh[ks] = *(const bf16x8*)&xh_lds[ai];
                axl[ks] = *(const bf16x8*)&xl_lds[ai];
            }
        }
        #pragma unroll
        for (int nt = 0; nt < 4; ++nt) {
            const int brow = nt * 16 + lr;
            #pragma unroll
            for (int ks = 0; ks < 4; ++ks) {
                const int bi = brow * HS + ((lk * 8 + ks * 32) ^ ((brow & 7) << 3));
                const bf16x8 bh = *(const bf16x8*)&wst[0][bi];
                const bf16x8 bl = *(const bf16x8*)&wst[1][bi];
                acc[c*4+nt] = __builtin_amdgcn_mfma_f32_16x16x32_bf16(axh[ks], bh, acc[c*4+nt], 0, 0, 0);
                acc[c*4+nt] = __builtin_amdgcn_mfma_f32_16x16x32_bf16(axl[ks], bh, acc[c*4+nt], 0, 0, 0);
                acc[c*4+nt] = __builtin_amdgcn_mfma_f32_16x16x32_bf16(axh[ks], bl, acc[c*4+nt], 0, 0, 0);
            }
        }
    }

    // ================= Phase 2: softmax stats (in-register) =================
    // lane holds option col = 16*i + lr for token row = w*16 + 4*lk + r
    float mx[4], rs[4];
    #pragma unroll
    for (int r = 0; r < 4; ++r) {
        float m = -3.0e38f;
        #pragma unroll
        for (int i = 0; i < 32; ++i) m = fmaxf(m, acc[i][r]);
        m *= invT;                                        // invT > 0
        #pragma unroll
        for (int s = 1; s < 16; s <<= 1) m = fmaxf(m, __shfl_xor(m, s));
        float sum = 0.f;
        #pragma unroll
        for (int i = 0; i < 32; ++i) sum += exp2f((acc[i][r] * invT - m) * LOG2E);
        #pragma unroll
        for (int s = 1; s < 16; s <<= 1) sum += __shfl_xor(sum, s);
        mx[r] = m;
        rs[r] = 1.0f / sum;
    }

    // ================= Phase 3: out = P @ C =================
    f32x4 oacc[8];
    #pragma unroll
    for (int i = 0; i < 8; ++i) oacc[i] = f32x4{0.f, 0.f, 0.f, 0.f};

    const int pr_ = t & 31;   // option-pair id (0..31)
    const int ag  = t >> 5;   // a-group (0..7)
    #pragma unroll
    for (int c = 0; c < 8; ++c) {
        __syncthreads();       // previous chunk's reads of wst done
        {   // stage C^T chunk: wst[0] viewed as [128 a][64 opt] bf16, packed-pair u32 writes
            const float* c0p = C + ((size_t)h * NOPT + c * KVB + 2 * pr_) * HS + ag * 16;
            float va[16], vb[16];
            #pragma unroll
            for (int q = 0; q < 4; ++q) {
                const float4 u0 = ((const float4*)c0p)[q];
                const float4 u1 = ((const float4*)(c0p + HS))[q];
                va[q*4+0] = u0.x; va[q*4+1] = u0.y; va[q*4+2] = u0.z; va[q*4+3] = u0.w;
                vb[q*4+0] = u1.x; vb[q*4+1] = u1.y; vb[q*4+2] = u1.z; vb[q*4+3] = u1.w;
            }
            unsigned* ct32 = (unsigned*)&wst[0][0];
            #pragma unroll
            for (int j = 0; j < 16; ++j) {
                const int a = ag * 16 + j;
                const unsigned pk = (unsigned)f2bf(va[j]) | ((unsigned)f2bf(vb[j]) << 16);
                ct32[a * 32 + (pr_ ^ ((a & 7) << 2))] = pk;   // row stride 32 u32
            }
        }
        // write this chunk's P into the per-wave LDS region
        #pragma unroll
        for (int nt = 0; nt < 4; ++nt) {
            #pragma unroll
            for (int r = 0; r < 4; ++r) {
                const float p = exp2f((acc[c*4+nt][r] * invT - mx[r]) * LOG2E);
                const int prow = lk * 4 + r;
                const int pcol = nt * 16 + lr;
                p_lds[w][prow * KVB + (pcol ^ ((prow & 7) << 3))] = f2bf(p);
            }
        }
        __syncthreads();       // C^T staged (p_lds is same-wave: compiler waits suffice)
        #pragma unroll
        for (int ks = 0; ks < 2; ++ks) {
            const int ai = lr * KVB + ((lk * 8 + ks * 32) ^ ((lr & 7) << 3));
            const bf16x8 pa = *(const bf16x8*)&p_lds[w][ai];
            #pragma unroll
            for (int nt = 0; nt < 8; ++nt) {
                const int brow = nt * 16 + lr;
                const int bi = brow * KVB + ((lk * 8 + ks * 32) ^ ((brow & 7) << 3));
                const bf16x8 cb = *(const bf16x8*)&wst[0][bi];
                oacc[nt] = __builtin_amdgcn_mfma_f32_16x16x32_bf16(pa, cb, oacc[nt], 0, 0, 0);
            }
        }
    }

    // ---- epilogue: scale by 1/sum, store ----
    #pragma unroll
    for (int nt = 0; nt < 8; ++nt) {
        #pragma unroll
        for (int r = 0; r < 4; ++r) {
            const int tok = n0 + w * 16 + lk * 4 + r;
            out[(size_t)tok * EMB + h * HS + nt * 16 + lr] = oacc[nt][r] * rs[r];
        }
    }
}

extern "C" void kernel_launch(void* const* d_in, const int* in_sizes, int n_in,
                              void* d_out, int out_size, void* d_ws, size_t ws_size,
                              hipStream_t stream) {
    const float* x = (const float*)d_in[0];
    const float* W = (const float*)d_in[1];
    const float* C = (const float*)d_in[2];
    const float* T = (const float*)d_in[3];
    float* out     = (float*)d_out;

    const int ntok = in_sizes[0] / EMB;            // 8192
    const int nblk = (ntok / TB) * NHEADS;         // 2048
    hipLaunchKernelGGL(vq_fwd_mfma, dim3(nblk), dim3(256), 0, stream,
                       x, W, C, T, out);
}

// Round 3
// 124.737 us; speedup vs baseline: 35.4337x; 1.3174x over previous
//
#include <hip/hip_runtime.h>
#include <math.h>

#define NHEADS 16
#define HS     128
#define NOPT   512
#define TB     64    // tokens per block (4 waves x 16)
#define KVB    64    // option chunk
#define NCH    (NOPT / KVB)   // 8 chunks
#define EMB    2048
#define LOG2E  1.44269504088896340736f

typedef short bf16x8 __attribute__((ext_vector_type(8)));
typedef unsigned short u16x8 __attribute__((ext_vector_type(8)));
typedef float f32x4 __attribute__((ext_vector_type(4)));

__device__ __forceinline__ unsigned short f2bf(float f) {
    union { float f; unsigned u; } v; v.f = f;
    unsigned r = v.u + 0x7FFFu + ((v.u >> 16) & 1u);   // rn-even
    return (unsigned short)(r >> 16);
}
__device__ __forceinline__ float bf2f(unsigned short h) {
    union { unsigned u; float f; } v; v.u = ((unsigned)h) << 16;
    return v.f;
}

// async global->LDS, 16B per lane. LDS dest = wave-uniform base + lane*16 (HW adds).
__device__ __forceinline__ void gll16(const void* gptr, void* lptr) {
    __builtin_amdgcn_global_load_lds(
        (const __attribute__((address_space(1))) void*)gptr,
        (__attribute__((address_space(3))) void*)lptr,
        16, 0, 0);
}

// ---------------- workspace image layout (ushorts) ----------------
// W images: [h][c][hi/lo][WIMG]  (chunk image = 64 opt rows x 128 cols, XOR-swizzled)
// C images: [h][c][WIMG]         (chunk image = C^T: 128 a rows x 64 opt cols, swizzled)
#define WIMG   (KVB * HS)                       // 8192 ushorts = 16KB
#define WS_C0  (NHEADS * NCH * 2 * WIMG)        // after W images (4MB)
#define WS_TOTAL_BYTES ((size_t)(WS_C0 + NHEADS * NCH * WIMG) * 2)   // 6MB

// P-write row->slot swizzle: rows {r,4+r,8+r,12+r} land in 4 distinct 16B slots.
#define PSW(row) ((((row) + ((row) >> 3)) & 7) << 3)

// ============ prep: f32 -> pre-swizzled bf16 chunk images in ws ============
__global__ __launch_bounds__(256) void vq_prep(const float* __restrict__ W,
                                               const float* __restrict__ C,
                                               unsigned short* __restrict__ ws)
{
    const int b = blockIdx.x;
    const int t = threadIdx.x;
    if (b < NHEADS * NCH) {                    // W chunk: hi/lo split
        const float* src = W + (size_t)b * KVB * HS;   // b = h*NCH + c
        unsigned short* dh = ws + (size_t)(b * 2) * WIMG;
        unsigned short* dl = dh + WIMG;
        for (int k = 0; k < 32; ++k) {
            const int e = k * 256 + t;
            const int row = e >> 7, col = e & 127;
            const float v = src[e];
            const unsigned short hb = f2bf(v);
            const unsigned short lb = f2bf(v - bf2f(hb));
            const int idx = row * HS + (col ^ ((row & 7) << 3));
            dh[idx] = hb;
            dl[idx] = lb;
        }
    } else {                                   // C chunk: transpose to [a][opt]
        const int b2 = b - NHEADS * NCH;
        const float* src = C + (size_t)b2 * KVB * HS;
        unsigned short* dst = ws + WS_C0 + (size_t)b2 * WIMG;
        for (int k = 0; k < 32; ++k) {
            const int e = k * 256 + t;
            const int opt = e >> 7, a = e & 127;
            dst[a * KVB + (opt ^ ((a & 7) << 3))] = f2bf(src[e]);
        }
    }
}

// ============ main: MFMA logits -> softmax -> MFMA PV ============
__global__ __launch_bounds__(256, 2) void vq_main(
    const float* __restrict__ x, const unsigned short* __restrict__ ws,
    const float* __restrict__ temp, float* __restrict__ out)
{
    __shared__ unsigned short wbuf[2][2 * WIMG];   // 64KB: W hi+lo chunk (dbuf); phase 3 reuses 16KB/buf for C
    __shared__ unsigned short p_lds[4][16 * KVB];  // 8KB: per-wave P chunk

    const int t  = threadIdx.x;
    const int l  = t & 63;
    const int w  = t >> 6;
    const int lr = l & 15;
    const int lk = l >> 4;
    const int b  = blockIdx.x;
    const int h    = ((b & 7) << 1) | ((b >> 3) & 1);   // 2 heads per XCD -> images fit per-XCD L2
    const int tile = b >> 4;
    const int n0   = tile * TB;
    const float invT = 1.0f / temp[0];

    // ---- issue DMA for W chunk 0 (overlaps with A-frag build) ----
    {
        const char* g = (const char*)(ws + (size_t)((h * NCH + 0) * 2) * WIMG) + w * 8192 + l * 16;
        char* lb = (char*)&wbuf[0][0] + w * 8192;
        #pragma unroll
        for (int i = 0; i < 8; ++i) gll16(g + i * 1024, lb + i * 1024);
    }

    // ---- A-fragments (x hi/lo) direct from global, fragment-shaped ----
    bf16x8 axh[4], axl[4];
    {
        const float* xr = x + (size_t)(n0 + w * 16 + lr) * EMB + h * HS + lk * 8;
        #pragma unroll
        for (int ks = 0; ks < 4; ++ks) {
            const float4 v0 = *(const float4*)(xr + ks * 32);
            const float4 v1 = *(const float4*)(xr + ks * 32 + 4);
            const float vv[8] = {v0.x, v0.y, v0.z, v0.w, v1.x, v1.y, v1.z, v1.w};
            u16x8 hh, ll;
            #pragma unroll
            for (int j = 0; j < 8; ++j) {
                const unsigned short hb = f2bf(vv[j]);
                hh[j] = hb;
                ll[j] = f2bf(vv[j] - bf2f(hb));
            }
            axh[ks] = (bf16x8)hh;
            axl[ks] = (bf16x8)ll;
        }
    }

    f32x4 acc[32];
    #pragma unroll
    for (int i = 0; i < 32; ++i) acc[i] = f32x4{0.f, 0.f, 0.f, 0.f};

    __syncthreads();   // compiler drains vmcnt before barrier -> chunk 0 ready

    // ================= Phase 1: logits, 2-phase pipelined =================
    for (int c = 0; c < NCH; ++c) {
        if (c + 1 < NCH) {   // issue next chunk's DMA before this chunk's MFMAs
            const char* g = (const char*)(ws + (size_t)((h * NCH + c + 1) * 2) * WIMG) + w * 8192 + l * 16;
            char* lb = (char*)&wbuf[(c + 1) & 1][0] + w * 8192;
            #pragma unroll
            for (int i = 0; i < 8; ++i) gll16(g + i * 1024, lb + i * 1024);
        }
        const unsigned short* wh = &wbuf[c & 1][0];
        const unsigned short* wl = wh + WIMG;
        #pragma unroll
        for (int nt = 0; nt < 4; ++nt) {
            const int brow = nt * 16 + lr;
            #pragma unroll
            for (int ks = 0; ks < 4; ++ks) {
                const int bi = brow * HS + ((lk * 8 + ks * 32) ^ ((brow & 7) << 3));
                const bf16x8 bh = *(const bf16x8*)&wh[bi];
                const bf16x8 bl = *(const bf16x8*)&wl[bi];
                acc[c * 4 + nt] = __builtin_amdgcn_mfma_f32_16x16x32_bf16(axh[ks], bh, acc[c * 4 + nt], 0, 0, 0);
                acc[c * 4 + nt] = __builtin_amdgcn_mfma_f32_16x16x32_bf16(axl[ks], bh, acc[c * 4 + nt], 0, 0, 0);
                acc[c * 4 + nt] = __builtin_amdgcn_mfma_f32_16x16x32_bf16(axh[ks], bl, acc[c * 4 + nt], 0, 0, 0);
            }
        }
        __syncthreads();   // drains next chunk's DMA; joins waves
    }

    // ---- issue DMA for C chunk 0 now; it runs under the softmax ----
    {
        const char* g = (const char*)(ws + WS_C0 + (size_t)(h * NCH + 0) * WIMG) + w * 4096 + l * 16;
        char* lb = (char*)&wbuf[0][0] + w * 4096;
        #pragma unroll
        for (int i = 0; i < 4; ++i) gll16(g + i * 1024, lb + i * 1024);
    }

    // ================= Phase 2: softmax stats (in-register) =================
    float mx[4], rs[4];
    #pragma unroll
    for (int r = 0; r < 4; ++r) {
        float m = -3.0e38f;
        #pragma unroll
        for (int i = 0; i < 32; ++i) m = fmaxf(m, acc[i][r]);
        m *= invT;
        #pragma unroll
        for (int s = 1; s < 16; s <<= 1) m = fmaxf(m, __shfl_xor(m, s));
        float sum = 0.f;
        #pragma unroll
        for (int i = 0; i < 32; ++i) sum += exp2f((acc[i][r] * invT - m) * LOG2E);
        #pragma unroll
        for (int s = 1; s < 16; s <<= 1) sum += __shfl_xor(sum, s);
        mx[r] = m;
        rs[r] = 1.0f / sum;
    }
    __syncthreads();   // C chunk 0 ready

    // ================= Phase 3: out = P @ C, 2-phase pipelined =================
    f32x4 oacc[8];
    #pragma unroll
    for (int i = 0; i < 8; ++i) oacc[i] = f32x4{0.f, 0.f, 0.f, 0.f};

    for (int cc = 0; cc < NCH; ++cc) {
        if (cc + 1 < NCH) {
            const char* g = (const char*)(ws + WS_C0 + (size_t)(h * NCH + cc + 1) * WIMG) + w * 4096 + l * 16;
            char* lb = (char*)&wbuf[(cc + 1) & 1][0] + w * 4096;
            #pragma unroll
            for (int i = 0; i < 4; ++i) gll16(g + i * 1024, lb + i * 1024);
        }
        // write this chunk's P (same-wave producer/consumer; no barrier needed)
        #pragma unroll
        for (int nt = 0; nt < 4; ++nt) {
            #pragma unroll
            for (int r = 0; r < 4; ++r) {
                const float p = exp2f((acc[cc * 4 + nt][r] * invT - mx[r]) * LOG2E);
                const int prow = lk * 4 + r;
                const int pcol = nt * 16 + lr;
                p_lds[w][prow * KVB + (pcol ^ PSW(prow))] = f2bf(p);
            }
        }
        const unsigned short* cb = &wbuf[cc & 1][0];
        #pragma unroll
        for (int ks = 0; ks < 2; ++ks) {
            const int ai = lr * KVB + ((lk * 8 + ks * 32) ^ PSW(lr));
            const bf16x8 pa = *(const bf16x8*)&p_lds[w][ai];
            #pragma unroll
            for (int nt = 0; nt < 8; ++nt) {
                const int a = nt * 16 + lr;
                const int bi = a * KVB + ((lk * 8 + ks * 32) ^ ((a & 7) << 3));
                const bf16x8 cfr = *(const bf16x8*)&cb[bi];
                oacc[nt] = __builtin_amdgcn_mfma_f32_16x16x32_bf16(pa, cfr, oacc[nt], 0, 0, 0);
            }
        }
        __syncthreads();
    }

    // ---- epilogue ----
    #pragma unroll
    for (int nt = 0; nt < 8; ++nt) {
        #pragma unroll
        for (int r = 0; r < 4; ++r) {
            const int tok = n0 + w * 16 + lk * 4 + r;
            out[(size_t)tok * EMB + h * HS + nt * 16 + lr] = oacc[nt][r] * rs[r];
        }
    }
}

// ============ fallback (Round-2 kernel, used only if ws is too small) ============
__global__ __launch_bounds__(256, 2) void vq_fwd_mfma(
    const float* __restrict__ x, const float* __restrict__ W,
    const float* __restrict__ C, const float* __restrict__ temp,
    float* __restrict__ out)
{
    __shared__ unsigned short xh_lds[TB * HS];
    __shared__ unsigned short xl_lds[TB * HS];
    __shared__ unsigned short wst[2][KVB * HS];
    __shared__ unsigned short p_lds[4][16 * KVB];

    const int t = threadIdx.x, l = t & 63, w = t >> 6, lr = l & 15, lk = l >> 4;
    const int b = blockIdx.x;
    const int h = ((b & 7) << 1) | ((b >> 3) & 1);
    const int tile = b >> 4, n0 = tile * TB;
    const float invT = 1.0f / temp[0];

    #pragma unroll
    for (int kk = 0; kk < 4; ++kk) {
        const int g = t + 256 * kk;
        const int row = g >> 4, c8 = (g & 15) * 8;
        const float* src = x + (size_t)(n0 + row) * EMB + h * HS + c8;
        const float4 v0 = *(const float4*)src;
        const float4 v1 = *(const float4*)(src + 4);
        float vv[8] = {v0.x, v0.y, v0.z, v0.w, v1.x, v1.y, v1.z, v1.w};
        u16x8 hh, ll;
        #pragma unroll
        for (int j = 0; j < 8; ++j) {
            const unsigned short hb = f2bf(vv[j]);
            hh[j] = hb; ll[j] = f2bf(vv[j] - bf2f(hb));
        }
        const int idx = row * HS + (c8 ^ ((row & 7) << 3));
        *(u16x8*)&xh_lds[idx] = hh;
        *(u16x8*)&xl_lds[idx] = ll;
    }

    f32x4 acc[32];
    #pragma unroll
    for (int i = 0; i < 32; ++i) acc[i] = f32x4{0.f, 0.f, 0.f, 0.f};
    bf16x8 axh[4], axl[4];

    #pragma unroll
    for (int c = 0; c < 8; ++c) {
        if (c) __syncthreads();
        #pragma unroll
        for (int kk = 0; kk < 4; ++kk) {
            const int g = t + 256 * kk;
            const int row = g >> 4, c8 = (g & 15) * 8;
            const float* src = W + ((size_t)h * NOPT + c * KVB + row) * HS + c8;
            const float4 v0 = *(const float4*)src;
            const float4 v1 = *(const float4*)(src + 4);
            float vv[8] = {v0.x, v0.y, v0.z, v0.w, v1.x, v1.y, v1.z, v1.w};
            u16x8 hh, ll;
            #pragma unroll
            for (int j = 0; j < 8; ++j) {
                const unsigned short hb = f2bf(vv[j]);
                hh[j] = hb; ll[j] = f2bf(vv[j] - bf2f(hb));
            }
            const int idx = row * HS + (c8 ^ ((row & 7) << 3));
            *(u16x8*)&wst[0][idx] = hh;
            *(u16x8*)&wst[1][idx] = ll;
        }
        __syncthreads();
        if (c == 0) {
            const int arow = w * 16 + lr;
            #pragma unroll
            for (int ks = 0; ks < 4; ++ks) {
                const int ai = arow * HS + ((lk * 8 + ks * 32) ^ ((arow & 7) << 3));
                axh[ks] = *(const bf16x8*)&xh_lds[ai];
                axl[ks] = *(const bf16x8*)&xl_lds[ai];
            }
        }
        #pragma unroll
        for (int nt = 0; nt < 4; ++nt) {
            const int brow = nt * 16 + lr;
            #pragma unroll
            for (int ks = 0; ks < 4; ++ks) {
                const int bi = brow * HS + ((lk * 8 + ks * 32) ^ ((brow & 7) << 3));
                const bf16x8 bh = *(const bf16x8*)&wst[0][bi];
                const bf16x8 bl = *(const bf16x8*)&wst[1][bi];
                acc[c*4+nt] = __builtin_amdgcn_mfma_f32_16x16x32_bf16(axh[ks], bh, acc[c*4+nt], 0, 0, 0);
                acc[c*4+nt] = __builtin_amdgcn_mfma_f32_16x16x32_bf16(axl[ks], bh, acc[c*4+nt], 0, 0, 0);
                acc[c*4+nt] = __builtin_amdgcn_mfma_f32_16x16x32_bf16(axh[ks], bl, acc[c*4+nt], 0, 0, 0);
            }
        }
    }

    float mx[4], rs[4];
    #pragma unroll
    for (int r = 0; r < 4; ++r) {
        float m = -3.0e38f;
        #pragma unroll
        for (int i = 0; i < 32; ++i) m = fmaxf(m, acc[i][r]);
        m *= invT;
        #pragma unroll
        for (int s = 1; s < 16; s <<= 1) m = fmaxf(m, __shfl_xor(m, s));
        float sum = 0.f;
        #pragma unroll
        for (int i = 0; i < 32; ++i) sum += exp2f((acc[i][r] * invT - m) * LOG2E);
        #pragma unroll
        for (int s = 1; s < 16; s <<= 1) sum += __shfl_xor(sum, s);
        mx[r] = m; rs[r] = 1.0f / sum;
    }

    f32x4 oacc[8];
    #pragma unroll
    for (int i = 0; i < 8; ++i) oacc[i] = f32x4{0.f, 0.f, 0.f, 0.f};
    const int pr_ = t & 31, ag = t >> 5;
    #pragma unroll
    for (int c = 0; c < 8; ++c) {
        __syncthreads();
        {
            const float* c0p = C + ((size_t)h * NOPT + c * KVB + 2 * pr_) * HS + ag * 16;
            float va[16], vb[16];
            #pragma unroll
            for (int q = 0; q < 4; ++q) {
                const float4 u0 = ((const float4*)c0p)[q];
                const float4 u1 = ((const float4*)(c0p + HS))[q];
                va[q*4+0] = u0.x; va[q*4+1] = u0.y; va[q*4+2] = u0.z; va[q*4+3] = u0.w;
                vb[q*4+0] = u1.x; vb[q*4+1] = u1.y; vb[q*4+2] = u1.z; vb[q*4+3] = u1.w;
            }
            unsigned* ct32 = (unsigned*)&wst[0][0];
            #pragma unroll
            for (int j = 0; j < 16; ++j) {
                const int a = ag * 16 + j;
                const unsigned pk = (unsigned)f2bf(va[j]) | ((unsigned)f2bf(vb[j]) << 16);
                ct32[a * 32 + (pr_ ^ ((a & 7) << 2))] = pk;
            }
        }
        #pragma unroll
        for (int nt = 0; nt < 4; ++nt) {
            #pragma unroll
            for (int r = 0; r < 4; ++r) {
                const float p = exp2f((acc[c*4+nt][r] * invT - mx[r]) * LOG2E);
                const int prow = lk * 4 + r;
                const int pcol = nt * 16 + lr;
                p_lds[w][prow * KVB + (pcol ^ ((prow & 7) << 3))] = f2bf(p);
            }
        }
        __syncthreads();
        #pragma unroll
        for (int ks = 0; ks < 2; ++ks) {
            const int ai = lr * KVB + ((lk * 8 + ks * 32) ^ ((lr & 7) << 3));
            const bf16x8 pa = *(const bf16x8*)&p_lds[w][ai];
            #pragma unroll
            for (int nt = 0; nt < 8; ++nt) {
                const int brow = nt * 16 + lr;
                const int bi = brow * KVB + ((lk * 8 + ks * 32) ^ ((brow & 7) << 3));
                const bf16x8 cbv = *(const bf16x8*)&wst[0][bi];
                oacc[nt] = __builtin_amdgcn_mfma_f32_16x16x32_bf16(pa, cbv, oacc[nt], 0, 0, 0);
            }
        }
    }

    #pragma unroll
    for (int nt = 0; nt < 8; ++nt) {
        #pragma unroll
        for (int r = 0; r < 4; ++r) {
            const int tok = n0 + w * 16 + lk * 4 + r;
            out[(size_t)tok * EMB + h * HS + nt * 16 + lr] = oacc[nt][r] * rs[r];
        }
    }
}

extern "C" void kernel_launch(void* const* d_in, const int* in_sizes, int n_in,
                              void* d_out, int out_size, void* d_ws, size_t ws_size,
                              hipStream_t stream) {
    const float* x = (const float*)d_in[0];
    const float* W = (const float*)d_in[1];
    const float* C = (const float*)d_in[2];
    const float* T = (const float*)d_in[3];
    float* out     = (float*)d_out;

    const int ntok = in_sizes[0] / EMB;            // 8192
    const int nblk = (ntok / TB) * NHEADS;         // 2048

    if (ws_size >= WS_TOTAL_BYTES) {
        hipLaunchKernelGGL(vq_prep, dim3(NHEADS * NCH * 2), dim3(256), 0, stream,
                           W, C, (unsigned short*)d_ws);
        hipLaunchKernelGGL(vq_main, dim3(nblk), dim3(256), 0, stream,
                           x, (const unsigned short*)d_ws, T, out);
    } else {
        hipLaunchKernelGGL(vq_fwd_mfma, dim3(nblk), dim3(256), 0, stream,
                           x, W, C, T, out);
    }
}

// Round 4
// 99.048 us; speedup vs baseline: 44.6235x; 1.2594x over previous
//
#include <hip/hip_runtime.h>
#include <math.h>

#define NHEADS 16
#define HS     128
#define NOPT   512
#define TB     128      // tokens per block (4 waves x 32)
#define OC     32       // options per chunk
#define NCH    16       // chunks
#define EMB    2048
#define LOG2E  1.44269504088896340736f
#define THRD   11.0f    // defer-max threshold (log2 units): P <= 2^11, f32 sum safe

typedef short bf16x8 __attribute__((ext_vector_type(8)));
typedef unsigned short u16x8 __attribute__((ext_vector_type(8)));
typedef float f32x4 __attribute__((ext_vector_type(4)));
typedef float f32x16 __attribute__((ext_vector_type(16)));
typedef unsigned u32x4 __attribute__((ext_vector_type(4)));

__device__ __forceinline__ unsigned short f2bf(float f) {
    union { float f; unsigned u; } v; v.f = f;
    unsigned r = v.u + 0x7FFFu + ((v.u >> 16) & 1u);   // rn-even
    return (unsigned short)(r >> 16);
}
__device__ __forceinline__ float bf2f(unsigned short h) {
    union { unsigned u; float f; } v; v.u = ((unsigned)h) << 16;
    return v.f;
}
__device__ __forceinline__ void gll16(const void* gptr, void* lptr) {
    __builtin_amdgcn_global_load_lds(
        (const __attribute__((address_space(1))) void*)gptr,
        (__attribute__((address_space(3))) void*)lptr,
        16, 0, 0);
}
__device__ __forceinline__ unsigned cvtpk(float lo, float hi) {
    unsigned r;
    asm("v_cvt_pk_bf16_f32 %0, %1, %2" : "=v"(r) : "v"(lo), "v"(hi));
    return r;
}
// v_permlane32_swap_b32: exchanges a.hi32 <-> b.lo32:
//   a' = {a.lo, b.lo_old}, b' = {a.hi_old, b.hi}
__device__ __forceinline__ void pl32swap(unsigned &a, unsigned &b) {
    asm volatile("v_permlane32_swap_b32 %0, %1" : "+v"(a), "+v"(b));
}
__device__ __forceinline__ f32x16 mfma32(bf16x8 a, bf16x8 b, f32x16 c) {
    return __builtin_amdgcn_mfma_f32_32x32x16_bf16(a, b, c, 0, 0, 0);
}

// ---------------- workspace image layout (ushorts) ----------------
// W: [h][c] chunk = 32 opt x 128 k bf16, hi(4096)+lo(4096), row-swizzled col^((opt&15)<<3)
// C: [h][c] chunk = C^T 128 a x 32 opt bf16, swizzled opt^(((a>>1)&3)<<3)
#define WCH    8192
#define CCH    4096
#define WS_C0  (NHEADS * NCH * WCH)                              // 4 MB worth
#define WS_TOTAL_BYTES ((size_t)(WS_C0 + NHEADS * NCH * CCH) * 2) // 6 MB

// ============ prep: f32 -> pre-swizzled bf16 chunk images ============
__global__ __launch_bounds__(256) void vq_prep(const float* __restrict__ W,
                                               const float* __restrict__ C,
                                               unsigned short* __restrict__ ws)
{
    const int b = blockIdx.x, t = threadIdx.x;
    if (b < NHEADS * NCH) {                 // W chunk, hi/lo split
        const float* src = W + (size_t)b * OC * HS;
        unsigned short* dh = ws + (size_t)b * WCH;
        unsigned short* dl = dh + 4096;
        for (int k = 0; k < 16; ++k) {
            const int e = k * 256 + t;      // 4096 elems
            const int opt = e >> 7, col = e & 127;
            const float v = src[e];
            const unsigned short hb = f2bf(v);
            const int idx = opt * 128 + (col ^ ((opt & 15) << 3));
            dh[idx] = hb;
            dl[idx] = f2bf(v - bf2f(hb));
        }
    } else {                                // C chunk -> C^T[a][opt]
        const int b2 = b - NHEADS * NCH;
        const float* src = C + (size_t)b2 * OC * HS;
        unsigned short* dst = ws + WS_C0 + (size_t)b2 * CCH;
        for (int k = 0; k < 16; ++k) {
            const int e = k * 256 + t;
            const int opt = e >> 7, a = e & 127;
            dst[a * 32 + (opt ^ (((a >> 1) & 3) << 3))] = f2bf(src[e]);
        }
    }
}

// ============ main: swapped-QK 32x32 MFMA, online softmax, in-reg P ============
__global__ __launch_bounds__(256, 2) void vq_main(
    const float* __restrict__ x, const unsigned short* __restrict__ ws,
    const float* __restrict__ temp, float* __restrict__ out)
{
    __shared__ unsigned short wbuf[2][WCH];   // 32 KB (dbuf W hi+lo chunk)
    __shared__ unsigned short cbuf[2][CCH];   // 16 KB (dbuf C^T chunk)

    const int t = threadIdx.x, l = t & 63, w = t >> 6;
    const int la = l & 31, hf = l >> 5;
    const int b = blockIdx.x;
    const int head = ((b & 7) << 1) | ((b >> 3) & 1);   // 2 heads per XCD
    const int n0 = (b >> 4) * TB;

    // ---- DMA chunk 0 (flies under x-prologue) ----
    {
        const char* gw = (const char*)(ws + (size_t)(head * NCH) * WCH) + w * 4096 + l * 16;
        char* lw = (char*)&wbuf[0][0] + w * 4096;
        #pragma unroll
        for (int i = 0; i < 4; ++i) gll16(gw + i * 1024, lw + i * 1024);
        const char* gc = (const char*)(ws + WS_C0 + (size_t)(head * NCH) * CCH) + w * 2048 + l * 16;
        char* lc = (char*)&cbuf[0][0] + w * 2048;
        #pragma unroll
        for (int i = 0; i < 2; ++i) gll16(gc + i * 1024, lc + i * 1024);
    }

    // ---- x row as B-fragments, scaled by invT*log2e, hi/lo split (64 VGPR) ----
    const float sc = (1.0f / temp[0]) * LOG2E;
    bf16x8 xhi[8], xlo[8];
    {
        const float* xr = x + (size_t)(n0 + w * 32 + la) * EMB + head * HS + hf * 8;
        #pragma unroll
        for (int kb = 0; kb < 8; ++kb) {
            const float4 v0 = *(const float4*)(xr + kb * 16);
            const float4 v1 = *(const float4*)(xr + kb * 16 + 4);
            const float vv[8] = {v0.x, v0.y, v0.z, v0.w, v1.x, v1.y, v1.z, v1.w};
            u16x8 hh, ll;
            #pragma unroll
            for (int j = 0; j < 8; ++j) {
                const float f = vv[j] * sc;
                const unsigned short hb = f2bf(f);
                hh[j] = hb;
                ll[j] = f2bf(f - bf2f(hb));
            }
            xhi[kb] = (bf16x8)hh;
            xlo[kb] = (bf16x8)ll;
        }
    }

    f32x16 O0 = (f32x16)0.0f, O1 = (f32x16)0.0f, O2 = (f32x16)0.0f, O3 = (f32x16)0.0f;
    float M = -1.0e30f, sacc = 0.0f;

    __syncthreads();   // drains chunk-0 DMA

    for (int c = 0; c < NCH; ++c) {
        const int cur = c & 1;
        if (c + 1 < NCH) {   // prefetch next chunk (whole chunk of compute to cover it)
            const char* gw = (const char*)(ws + (size_t)(head * NCH + c + 1) * WCH) + w * 4096 + l * 16;
            char* lw = (char*)&wbuf[cur ^ 1][0] + w * 4096;
            #pragma unroll
            for (int i = 0; i < 4; ++i) gll16(gw + i * 1024, lw + i * 1024);
            const char* gc = (const char*)(ws + WS_C0 + (size_t)(head * NCH + c + 1) * CCH) + w * 2048 + l * 16;
            char* lc = (char*)&cbuf[cur ^ 1][0] + w * 2048;
            #pragma unroll
            for (int i = 0; i < 2; ++i) gll16(gc + i * 1024, lc + i * 1024);
        }

        // ---- QK^T swapped: S^T[opt][tok] = W · x^T; A=W (LDS), B=x (regs) ----
        f32x16 sa = (f32x16)0.0f, sb = (f32x16)0.0f;   // 2 chains for MFMA ILP
        const unsigned short* wb = &wbuf[cur][0];
        #pragma unroll
        for (int kb = 0; kb < 8; ++kb) {
            const int idx = la * 128 + ((kb * 16 + hf * 8) ^ ((la & 15) << 3));
            const bf16x8 whi = *(const bf16x8*)&wb[idx];
            const bf16x8 wlo = *(const bf16x8*)&wb[idx + 4096];
            if (kb & 1) {
                sb = mfma32(whi, xhi[kb], sb);
                sb = mfma32(whi, xlo[kb], sb);
                sb = mfma32(wlo, xhi[kb], sb);
            } else {
                sa = mfma32(whi, xhi[kb], sa);
                sa = mfma32(whi, xlo[kb], sa);
                sa = mfma32(wlo, xhi[kb], sa);
            }
        }
        const f32x16 S = sa + sb;   // S already in log2 units (invT*log2e folded into x)

        // ---- online softmax (per token = per lane; rows are options) ----
        float cmax = S[0];
        #pragma unroll
        for (int q = 1; q < 16; ++q) cmax = fmaxf(cmax, S[q]);
        cmax = fmaxf(cmax, __shfl_xor(cmax, 32));
        if (__any(cmax > M + THRD)) {          // rare rescale (defer-max, T13)
            const float Mn = fmaxf(M, cmax);
            const float fr = exp2f(M - Mn);    // first chunk: exp2(-1e30)=0
            M = Mn;
            sacc *= fr;
            #pragma unroll
            for (int q = 0; q < 16; ++q) {
                const int row = (q & 3) + 8 * (q >> 2) + 4 * hf;
                const float f = __shfl(fr, row);
                O0[q] *= f; O1[q] *= f; O2[q] *= f; O3[q] *= f;
            }
        }
        float pv[16];
        float ps = 0.0f;
        #pragma unroll
        for (int q = 0; q < 16; ++q) { pv[q] = exp2f(S[q] - M); ps += pv[q]; }
        sacc += ps;

        // ---- P -> bf16 A-fragments fully in-register (T12) ----
        unsigned pk0 = cvtpk(pv[0],  pv[1]),  pk1 = cvtpk(pv[2],  pv[3]);
        unsigned pk2 = cvtpk(pv[4],  pv[5]),  pk3 = cvtpk(pv[6],  pv[7]);
        unsigned pk4 = cvtpk(pv[8],  pv[9]),  pk5 = cvtpk(pv[10], pv[11]);
        unsigned pk6 = cvtpk(pv[12], pv[13]), pk7 = cvtpk(pv[14], pv[15]);
        pl32swap(pk0, pk2);   // -> kb0 slot0 / slot2
        pl32swap(pk1, pk3);   // -> kb0 slot1 / slot3
        pl32swap(pk4, pk6);   // -> kb1 slot0 / slot2
        pl32swap(pk5, pk7);   // -> kb1 slot1 / slot3
        const bf16x8 pa0 = __builtin_bit_cast(bf16x8, (u32x4){pk0, pk1, pk2, pk3});
        const bf16x8 pa1 = __builtin_bit_cast(bf16x8, (u32x4){pk4, pk5, pk6, pk7});

        // ---- PV: O += P · C  (A=P regs, B=C^T LDS) ----
        const unsigned short* cb = &cbuf[cur][0];
        {
            const int a0 = la;
            const int sw0 = ((a0 >> 1) & 3) << 3;
            O0 = mfma32(pa0, *(const bf16x8*)&cb[a0 * 32 + ((hf * 8) ^ sw0)], O0);
            O0 = mfma32(pa1, *(const bf16x8*)&cb[a0 * 32 + ((16 + hf * 8) ^ sw0)], O0);
            const int a1 = 32 + la;
            const int sw1 = ((a1 >> 1) & 3) << 3;
            O1 = mfma32(pa0, *(const bf16x8*)&cb[a1 * 32 + ((hf * 8) ^ sw1)], O1);
            O1 = mfma32(pa1, *(const bf16x8*)&cb[a1 * 32 + ((16 + hf * 8) ^ sw1)], O1);
            const int a2 = 64 + la;
            const int sw2 = ((a2 >> 1) & 3) << 3;
            O2 = mfma32(pa0, *(const bf16x8*)&cb[a2 * 32 + ((hf * 8) ^ sw2)], O2);
            O2 = mfma32(pa1, *(const bf16x8*)&cb[a2 * 32 + ((16 + hf * 8) ^ sw2)], O2);
            const int a3 = 96 + la;
            const int sw3 = ((a3 >> 1) & 3) << 3;
            O3 = mfma32(pa0, *(const bf16x8*)&cb[a3 * 32 + ((hf * 8) ^ sw3)], O3);
            O3 = mfma32(pa1, *(const bf16x8*)&cb[a3 * 32 + ((16 + hf * 8) ^ sw3)], O3);
        }
        __syncthreads();   // drains next-chunk DMA; separates buffer reuse
    }

    // ---- epilogue: normalize by 1/sum, coalesced stores ----
    const float stot = sacc + __shfl_xor(sacc, 32);
    const float rs = 1.0f / stot;
    #pragma unroll
    for (int q = 0; q < 16; ++q) {
        const int row = (q & 3) + 8 * (q >> 2) + 4 * hf;
        const float rq = __shfl(rs, row);
        float* op = out + (size_t)(n0 + w * 32 + row) * EMB + head * HS + la;
        op[0]  = O0[q] * rq;
        op[32] = O1[q] * rq;
        op[64] = O2[q] * rq;
        op[96] = O3[q] * rq;
    }
}

// ============ fallback (Round-2 kernel, no workspace needed) ============
__global__ __launch_bounds__(256, 2) void vq_fwd_mfma(
    const float* __restrict__ x, const float* __restrict__ W,
    const float* __restrict__ C, const float* __restrict__ temp,
    float* __restrict__ out)
{
    __shared__ unsigned short xh_lds[64 * HS];
    __shared__ unsigned short xl_lds[64 * HS];
    __shared__ unsigned short wst[2][64 * HS];
    __shared__ unsigned short p_lds[4][16 * 64];

    const int t = threadIdx.x, l = t & 63, w = t >> 6, lr = l & 15, lk = l >> 4;
    const int b = blockIdx.x;
    const int h = ((b & 7) << 1) | ((b >> 3) & 1);
    const int n0 = (b >> 4) * 64;
    const float invT = 1.0f / temp[0];

    #pragma unroll
    for (int kk = 0; kk < 4; ++kk) {
        const int g = t + 256 * kk;
        const int row = g >> 4, c8 = (g & 15) * 8;
        const float* src = x + (size_t)(n0 + row) * EMB + h * HS + c8;
        const float4 v0 = *(const float4*)src;
        const float4 v1 = *(const float4*)(src + 4);
        float vv[8] = {v0.x, v0.y, v0.z, v0.w, v1.x, v1.y, v1.z, v1.w};
        u16x8 hh, ll;
        #pragma unroll
        for (int j = 0; j < 8; ++j) {
            const unsigned short hb = f2bf(vv[j]);
            hh[j] = hb; ll[j] = f2bf(vv[j] - bf2f(hb));
        }
        const int idx = row * HS + (c8 ^ ((row & 7) << 3));
        *(u16x8*)&xh_lds[idx] = hh;
        *(u16x8*)&xl_lds[idx] = ll;
    }

    f32x4 acc[32];
    #pragma unroll
    for (int i = 0; i < 32; ++i) acc[i] = f32x4{0.f, 0.f, 0.f, 0.f};
    bf16x8 axh[4], axl[4];

    #pragma unroll
    for (int c = 0; c < 8; ++c) {
        if (c) __syncthreads();
        #pragma unroll
        for (int kk = 0; kk < 4; ++kk) {
            const int g = t + 256 * kk;
            const int row = g >> 4, c8 = (g & 15) * 8;
            const float* src = W + ((size_t)h * NOPT + c * 64 + row) * HS + c8;
            const float4 v0 = *(const float4*)src;
            const float4 v1 = *(const float4*)(src + 4);
            float vv[8] = {v0.x, v0.y, v0.z, v0.w, v1.x, v1.y, v1.z, v1.w};
            u16x8 hh, ll;
            #pragma unroll
            for (int j = 0; j < 8; ++j) {
                const unsigned short hb = f2bf(vv[j]);
                hh[j] = hb; ll[j] = f2bf(vv[j] - bf2f(hb));
            }
            const int idx = row * HS + (c8 ^ ((row & 7) << 3));
            *(u16x8*)&wst[0][idx] = hh;
            *(u16x8*)&wst[1][idx] = ll;
        }
        __syncthreads();
        if (c == 0) {
            const int arow = w * 16 + lr;
            #pragma unroll
            for (int ks = 0; ks < 4; ++ks) {
                const int ai = arow * HS + ((lk * 8 + ks * 32) ^ ((arow & 7) << 3));
                axh[ks] = *(const bf16x8*)&xh_lds[ai];
                axl[ks] = *(const bf16x8*)&xl_lds[ai];
            }
        }
        #pragma unroll
        for (int nt = 0; nt < 4; ++nt) {
            const int brow = nt * 16 + lr;
            #pragma unroll
            for (int ks = 0; ks < 4; ++ks) {
                const int bi = brow * HS + ((lk * 8 + ks * 32) ^ ((brow & 7) << 3));
                const bf16x8 bh = *(const bf16x8*)&wst[0][bi];
                const bf16x8 bl = *(const bf16x8*)&wst[1][bi];
                acc[c*4+nt] = __builtin_amdgcn_mfma_f32_16x16x32_bf16(axh[ks], bh, acc[c*4+nt], 0, 0, 0);
                acc[c*4+nt] = __builtin_amdgcn_mfma_f32_16x16x32_bf16(axl[ks], bh, acc[c*4+nt], 0, 0, 0);
                acc[c*4+nt] = __builtin_amdgcn_mfma_f32_16x16x32_bf16(axh[ks], bl, acc[c*4+nt], 0, 0, 0);
            }
        }
    }

    float mx[4], rsn[4];
    #pragma unroll
    for (int r = 0; r < 4; ++r) {
        float m = -3.0e38f;
        #pragma unroll
        for (int i = 0; i < 32; ++i) m = fmaxf(m, acc[i][r]);
        m *= invT;
        #pragma unroll
        for (int s = 1; s < 16; s <<= 1) m = fmaxf(m, __shfl_xor(m, s));
        float sum = 0.f;
        #pragma unroll
        for (int i = 0; i < 32; ++i) sum += exp2f((acc[i][r] * invT - m) * LOG2E);
        #pragma unroll
        for (int s = 1; s < 16; s <<= 1) sum += __shfl_xor(sum, s);
        mx[r] = m; rsn[r] = 1.0f / sum;
    }

    f32x4 oacc[8];
    #pragma unroll
    for (int i = 0; i < 8; ++i) oacc[i] = f32x4{0.f, 0.f, 0.f, 0.f};
    const int pr_ = t & 31, ag = t >> 5;
    #pragma unroll
    for (int c = 0; c < 8; ++c) {
        __syncthreads();
        {
            const float* c0p = C + ((size_t)h * NOPT + c * 64 + 2 * pr_) * HS + ag * 16;
            float va[16], vb[16];
            #pragma unroll
            for (int q = 0; q < 4; ++q) {
                const float4 u0 = ((const float4*)c0p)[q];
                const float4 u1 = ((const float4*)(c0p + HS))[q];
                va[q*4+0] = u0.x; va[q*4+1] = u0.y; va[q*4+2] = u0.z; va[q*4+3] = u0.w;
                vb[q*4+0] = u1.x; vb[q*4+1] = u1.y; vb[q*4+2] = u1.z; vb[q*4+3] = u1.w;
            }
            unsigned* ct32 = (unsigned*)&wst[0][0];
            #pragma unroll
            for (int j = 0; j < 16; ++j) {
                const int a = ag * 16 + j;
                const unsigned pkv = (unsigned)f2bf(va[j]) | ((unsigned)f2bf(vb[j]) << 16);
                ct32[a * 32 + (pr_ ^ ((a & 7) << 2))] = pkv;
            }
        }
        #pragma unroll
        for (int nt = 0; nt < 4; ++nt) {
            #pragma unroll
            for (int r = 0; r < 4; ++r) {
                const float p = exp2f((acc[c*4+nt][r] * invT - mx[r]) * LOG2E);
                const int prow = lk * 4 + r;
                const int pcol = nt * 16 + lr;
                p_lds[w][prow * 64 + (pcol ^ ((prow & 7) << 3))] = f2bf(p);
            }
        }
        __syncthreads();
        #pragma unroll
        for (int ks = 0; ks < 2; ++ks) {
            const int ai = lr * 64 + ((lk * 8 + ks * 32) ^ ((lr & 7) << 3));
            const bf16x8 pa = *(const bf16x8*)&p_lds[w][ai];
            #pragma unroll
            for (int nt = 0; nt < 8; ++nt) {
                const int brow = nt * 16 + lr;
                const int bi = brow * 64 + ((lk * 8 + ks * 32) ^ ((brow & 7) << 3));
                const bf16x8 cbv = *(const bf16x8*)&wst[0][bi];
                oacc[nt] = __builtin_amdgcn_mfma_f32_16x16x32_bf16(pa, cbv, oacc[nt], 0, 0, 0);
            }
        }
    }

    #pragma unroll
    for (int nt = 0; nt < 8; ++nt) {
        #pragma unroll
        for (int r = 0; r < 4; ++r) {
            const int tok = n0 + w * 16 + lk * 4 + r;
            out[(size_t)tok * EMB + h * HS + nt * 16 + lr] = oacc[nt][r] * rsn[r];
        }
    }
}

extern "C" void kernel_launch(void* const* d_in, const int* in_sizes, int n_in,
                              void* d_out, int out_size, void* d_ws, size_t ws_size,
                              hipStream_t stream) {
    const float* x = (const float*)d_in[0];
    const float* W = (const float*)d_in[1];
    const float* C = (const float*)d_in[2];
    const float* T = (const float*)d_in[3];
    float* out     = (float*)d_out;

    const int ntok = in_sizes[0] / EMB;   // 8192

    if (ws_size >= WS_TOTAL_BYTES) {
        hipLaunchKernelGGL(vq_prep, dim3(NHEADS * NCH * 2), dim3(256), 0, stream,
                           W, C, (unsigned short*)d_ws);
        const int nblk = (ntok / TB) * NHEADS;   // 1024
        hipLaunchKernelGGL(vq_main, dim3(nblk), dim3(256), 0, stream,
                           x, (const unsigned short*)d_ws, T, out);
    } else {
        const int nblk = (ntok / 64) * NHEADS;   // 2048
        hipLaunchKernelGGL(vq_fwd_mfma, dim3(nblk), dim3(256), 0, stream,
                           x, W, C, T, out);
    }
}